// Round 10
// baseline (504.203 us; speedup 1.0000x reference)
//
#include <hip/hip_runtime.h>
#include <hip/hip_bf16.h>
#include <stdint.h>

// x[65536][256] f32, memory[2048][256] f32
// out = [ memory_output[65536][256] | attention_weights[65536][2048] ] f32
#define NQ 65536
#define MM 2048
#define DD 256

typedef __bf16 bf16x8 __attribute__((ext_vector_type(8)));
typedef float f32x16 __attribute__((ext_vector_type(16)));
typedef unsigned short u16;
typedef unsigned int u32;
typedef u16 u16x8 __attribute__((ext_vector_type(8)));

typedef __attribute__((address_space(3))) u32 lds_u32;
typedef __attribute__((address_space(1))) u32 glb_u32;

#define GLOAD16(gsrc, ldst)                                                    \
  __builtin_amdgcn_global_load_lds((glb_u32*)(uintptr_t)(gsrc),                \
                                   (lds_u32*)(u32)(uintptr_t)(ldst), 16, 0, 0)

__device__ __forceinline__ u16 f32_to_bf16_rtne(float v) {
  u32 u = __builtin_bit_cast(u32, v);
  u += 0x7FFFu + ((u >> 16) & 1u);
  return (u16)(u >> 16);
}

// memb: row-major [2048][256] bf16.
// memTswz: per 32-m tile t (64 tiles, 16KB each):
//   u16 idx = t*8192 + (d*4 + slot)*8 + e, slot = c ^ ((d>>1)&3),
//   within-tile m = c*8 + e. (R5/R8-validated staging + PV read path.)
__global__ __launch_bounds__(256) void mem_convert_kernel(
    const float* __restrict__ memory, u16* __restrict__ memb,
    u16* __restrict__ memTswz) {
  int tid = blockIdx.x * 256 + threadIdx.x;  // 524288 total
  u16 b = f32_to_bf16_rtne(memory[tid]);
  memb[tid] = b;
  int m = tid >> 8, d = tid & 255;
  int t = m >> 5, mi = m & 31;
  int c = mi >> 3, e = mi & 7;
  int slot = c ^ ((d >> 1) & 3);
  memTswz[(size_t)t * 8192 + (size_t)(d * 4 + slot) * 8 + e] = b;
}

// ---- Fused pass: QK + exp -> e (bf16) + sums + O = (e*M)*(1/sum) ----
// 512 blocks x 4 waves x 32q; 64 iters over 32-m tiles; dbuf 2x(16+16)KB.
// Per iter: stage next memb+memT -> QK 16 MFMA -> exp/part/e-store/plds ->
// lgkmcnt -> PV 16 MFMA -> barrier. plds transpose validated in R2; e-store
// in R5+; PV slot-swizzle in R3+; O end-scale in R5+.
__global__ __launch_bounds__(256, 2) void pass1_kernel(
    const float* __restrict__ x, const u16* __restrict__ memb,
    const u16* __restrict__ memTswz, u16* __restrict__ p_e,
    float* __restrict__ sums, float* __restrict__ outO) {
  __shared__ __align__(16) char mb[2][16384];
  __shared__ __align__(16) char mt[2][16384];
  __shared__ __align__(16) u16 plds[4][32][40];  // 80B pitch

  const int tid = threadIdx.x;
  const int wv = tid >> 6;
  const int l = tid & 63;
  const int q5 = l & 31;
  const int h = l >> 5;
  const int qw = blockIdx.x * 128 + wv * 32;

  bf16x8 aq[16];
  {
    const float* xrow = x + (size_t)(qw + q5) * DD;
#pragma unroll
    for (int ks = 0; ks < 16; ++ks) {
      const float4 f0 = *(const float4*)(xrow + ks * 16 + h * 8);
      const float4 f1 = *(const float4*)(xrow + ks * 16 + h * 8 + 4);
      bf16x8 a;
      a[0] = (__bf16)f0.x; a[1] = (__bf16)f0.y;
      a[2] = (__bf16)f0.z; a[3] = (__bf16)f0.w;
      a[4] = (__bf16)f1.x; a[5] = (__bf16)f1.y;
      a[6] = (__bf16)f1.z; a[7] = (__bf16)f1.w;
      aq[ks] = a;
    }
  }

  auto STAGE_MB = [&](int t, char* buf) {  // 32 memb rows -> 16KB
#pragma unroll
    for (int i = 0; i < 4; ++i) {
      const int wc = wv * 4 + i;   // 1KB chunks 0..15
      const int row = wc * 2 + h;  // 0..31
      const int csrc = q5 ^ (row & 7);
      GLOAD16(memb + (((size_t)(t * 32 + row)) << 8) + csrc * 8,
              buf + (wc << 10));
    }
  };
  auto STAGE_MT = [&](int t, char* buf) {  // 16KB memT tile, linear
#pragma unroll
    for (int i = 0; i < 4; ++i) {
      const int ci = wv * 4 + i;
      GLOAD16(memTswz + ((size_t)t * 1024 + ci * 64 + l) * 8, buf + (ci << 10));
    }
  };

  float part[16];
#pragma unroll
  for (int r = 0; r < 16; ++r) part[r] = 0.f;
  f32x16 oacc[8];
#pragma unroll
  for (int i = 0; i < 8; ++i) oacc[i] = 0.f;

  STAGE_MB(0, mb[0]);
  STAGE_MT(0, mt[0]);
  __syncthreads();
  for (int t = 0; t < 64; ++t) {
    const int cur = t & 1;
    if (t + 1 < 64) {
      STAGE_MB(t + 1, mb[cur ^ 1]);
      STAGE_MT(t + 1, mt[cur ^ 1]);
    }

    // QK: S[32q][32m] over k=256 from mb[cur] (R5-validated read path)
    const char* bbase = mb[cur] + q5 * 512;
    const int sw = q5 & 7;
    f32x16 acc = 0.f;
    __builtin_amdgcn_s_setprio(1);
#pragma unroll
    for (int ks = 0; ks < 16; ++ks) {
      bf16x8 b = *(const bf16x8*)(bbase + (((ks * 2 + h) ^ sw) << 4));
      acc = __builtin_amdgcn_mfma_f32_32x32x16_bf16(aq[ks], b, acc, 0, 0, 0);
    }
    __builtin_amdgcn_s_setprio(0);

    // exp, rowsum parts, e-store (identity addressing) + plds for transpose
#pragma unroll
    for (int r = 0; r < 16; ++r) {
      const int qrow = (r & 3) + 8 * (r >> 2) + 4 * h;
      const float e = __expf(acc[r]);
      part[r] += e;
      const u16 eb = f32_to_bf16_rtne(e);
      p_e[(size_t)(qw + qrow) * MM + t * 32 + q5] = eb;
      plds[wv][qrow][q5] = eb;
    }
    // wave-private plds roundtrip: drain DS writes before reads
    asm volatile("s_waitcnt lgkmcnt(0)" ::: "memory");
    __builtin_amdgcn_sched_barrier(0);

    // PV: O += P(32q x 32m) * M(32m x 256d) from mt[cur]
    const char* ct = mt[cur];
    __builtin_amdgcn_s_setprio(1);
#pragma unroll
    for (int ks2 = 0; ks2 < 2; ++ks2) {
      const bf16x8 pa = *(const bf16x8*)&plds[wv][q5][ks2 * 16 + h * 8];
#pragma unroll
      for (int dsub = 0; dsub < 8; ++dsub) {
        const int d = dsub * 32 + q5;
        const int slot = (2 * ks2 + h) ^ ((d >> 1) & 3);
        bf16x8 b = *(const bf16x8*)(ct + d * 64 + slot * 16);
        oacc[dsub] =
            __builtin_amdgcn_mfma_f32_32x32x16_bf16(pa, b, oacc[dsub], 0, 0, 0);
      }
    }
    __builtin_amdgcn_s_setprio(0);
    __syncthreads();
  }

  // butterfly: every lane ends with the full rowsum in part[r]
#pragma unroll
  for (int r = 0; r < 16; ++r) {
    float p = part[r];
    p += __shfl_xor(p, 1, 64);
    p += __shfl_xor(p, 2, 64);
    p += __shfl_xor(p, 4, 64);
    p += __shfl_xor(p, 8, 64);
    p += __shfl_xor(p, 16, 64);
    part[r] = p;
  }
  if (q5 == 0) {
#pragma unroll
    for (int r = 0; r < 16; ++r) {
      sums[qw + (r & 3) + 8 * (r >> 2) + 4 * h] = part[r];
    }
  }

  // O write, scaled by 1/rowsum (row of part[r] == row of oacc[*][r])
#pragma unroll
  for (int dsub = 0; dsub < 8; ++dsub) {
#pragma unroll
    for (int r = 0; r < 16; ++r) {
      const int qrow = (r & 3) + 8 * (r >> 2) + 4 * h;
      outO[(size_t)(qw + qrow) * DD + dsub * 32 + q5] =
          oacc[dsub][r] / part[r];
    }
  }
}

// ---- W-stream: W = f32(e_bf16) * (1/sum), pure BW kernel ----
// 16384 blocks x 256. Thread owns 32 contiguous elems of one row:
// wave reads 4KB / writes 8KB contiguous. No LDS, no barriers.
__global__ __launch_bounds__(256) void wnorm_kernel(
    const u16* __restrict__ p_e, const float* __restrict__ sums,
    float* __restrict__ outW) {
  const int tid = blockIdx.x * 256 + threadIdx.x;
  const int row = tid >> 6;        // 64 chunks of 32 per row
  const int chunk = tid & 63;
  const float inv = 1.0f / sums[row];
  const u16* src = p_e + (size_t)row * MM + chunk * 32;
  float* dst = outW + (size_t)row * MM + chunk * 32;
#pragma unroll
  for (int j = 0; j < 4; ++j) {
    const u16x8 v = *(const u16x8*)(src + j * 8);
    float w[8];
#pragma unroll
    for (int k = 0; k < 8; ++k) {
      w[k] = __builtin_bit_cast(float, (u32)v[k] << 16) * inv;
    }
    *(float4*)(dst + j * 8) = make_float4(w[0], w[1], w[2], w[3]);
    *(float4*)(dst + j * 8 + 4) = make_float4(w[4], w[5], w[6], w[7]);
  }
}

// ---- Fallback (ws too small): f32-roundtrip via outW (R4/R5-validated) ----
__global__ __launch_bounds__(256, 2) void pass1_fb(
    const float* __restrict__ x, const u16* __restrict__ memb,
    float* __restrict__ outWf, float* __restrict__ sums) {
  __shared__ __align__(16) char stage[2][32768];
  const int tid = threadIdx.x;
  const int wv = tid >> 6;
  const int l = tid & 63;
  const int q5 = l & 31;
  const int h = l >> 5;
  const int qw = blockIdx.x * 128 + wv * 32;

  bf16x8 aq[16];
  {
    const float* xrow = x + (size_t)(qw + q5) * DD;
#pragma unroll
    for (int ks = 0; ks < 16; ++ks) {
      const float4 f0 = *(const float4*)(xrow + ks * 16 + h * 8);
      const float4 f1 = *(const float4*)(xrow + ks * 16 + h * 8 + 4);
      bf16x8 a;
      a[0] = (__bf16)f0.x; a[1] = (__bf16)f0.y;
      a[2] = (__bf16)f0.z; a[3] = (__bf16)f0.w;
      a[4] = (__bf16)f1.x; a[5] = (__bf16)f1.y;
      a[6] = (__bf16)f1.z; a[7] = (__bf16)f1.w;
      aq[ks] = a;
    }
  }
  auto STAGE1 = [&](int mt, char* buf) {
#pragma unroll
    for (int i = 0; i < 8; ++i) {
      const int wc = wv * 8 + i;
      const int row = wc * 2 + h;
      const int csrc = q5 ^ (row & 7);
      GLOAD16(memb + (((size_t)(mt * 64 + row)) << 8) + csrc * 8,
              buf + (wc << 10));
    }
  };
  float part[16];
#pragma unroll
  for (int r = 0; r < 16; ++r) part[r] = 0.f;
  STAGE1(0, stage[0]);
  __syncthreads();
  for (int mt = 0; mt < 32; ++mt) {
    char* cur = stage[mt & 1];
    char* nxt = stage[(mt & 1) ^ 1];
    if (mt + 1 < 32) STAGE1(mt + 1, nxt);
#pragma unroll
    for (int msub = 0; msub < 2; ++msub) {
      const int mrow = msub * 32 + q5;
      const char* bbase = cur + mrow * 512;
      const int sw = mrow & 7;
      f32x16 acc = 0.f;
#pragma unroll
      for (int ks = 0; ks < 16; ++ks) {
        bf16x8 b = *(const bf16x8*)(bbase + (((ks * 2 + h) ^ sw) << 4));
        acc = __builtin_amdgcn_mfma_f32_32x32x16_bf16(aq[ks], b, acc, 0, 0, 0);
      }
      const int tm = mt * 2 + msub;
#pragma unroll
      for (int r = 0; r < 16; ++r) {
        const int qrow = (r & 3) + 8 * (r >> 2) + 4 * h;
        const float e = __expf(acc[r]);
        part[r] += e;
        outWf[(size_t)(qw + qrow) * MM + tm * 32 + q5] = e;
      }
    }
    __syncthreads();
  }
#pragma unroll
  for (int r = 0; r < 16; ++r) {
    float s = part[r];
    s += __shfl_xor(s, 1, 64);
    s += __shfl_xor(s, 2, 64);
    s += __shfl_xor(s, 4, 64);
    s += __shfl_xor(s, 8, 64);
    s += __shfl_xor(s, 16, 64);
    if (q5 == 0) sums[qw + (r & 3) + 8 * (r >> 2) + 4 * h] = s;
  }
}

__global__ __launch_bounds__(256, 2) void pass2_fb(
    const u16* __restrict__ memTswz, const float* __restrict__ sums,
    float* __restrict__ outO, float* __restrict__ outW) {
  __shared__ __align__(16) char tstage[2][16384];
  const int tid = threadIdx.x;
  const int wv = tid >> 6;
  const int l = tid & 63;
  const int q5 = l & 31;
  const int h = l >> 5;
  const int qw = blockIdx.x * 128 + wv * 32;
  const float inv_lane = 1.0f / sums[qw + q5];
  auto STAGE = [&](int t, char* buf) {
#pragma unroll
    for (int i = 0; i < 4; ++i) {
      const int ci = wv * 4 + i;
      GLOAD16(memTswz + ((size_t)t * 1024 + ci * 64 + l) * 8, buf + (ci << 10));
    }
  };
  f32x16 oacc[8];
#pragma unroll
  for (int i = 0; i < 8; ++i) oacc[i] = 0.f;
  STAGE(0, tstage[0]);
  __syncthreads();
  for (int tm = 0; tm < 64; ++tm) {
    char* cur = tstage[tm & 1];
    char* nxt = tstage[(tm & 1) ^ 1];
    if (tm + 1 < 64) STAGE(tm + 1, nxt);
    float* wrow = outW + (size_t)(qw + q5) * MM + tm * 32;
    bf16x8 pa[2];
#pragma unroll
    for (int ks2 = 0; ks2 < 2; ++ks2) {
      float4 f0 = *(const float4*)(wrow + ks2 * 16 + h * 8);
      float4 f1 = *(const float4*)(wrow + ks2 * 16 + h * 8 + 4);
      float w0 = f0.x * inv_lane, w1 = f0.y * inv_lane;
      float w2 = f0.z * inv_lane, w3 = f0.w * inv_lane;
      float w4 = f1.x * inv_lane, w5 = f1.y * inv_lane;
      float w6 = f1.z * inv_lane, w7 = f1.w * inv_lane;
      *(float4*)(wrow + ks2 * 16 + h * 8) = make_float4(w0, w1, w2, w3);
      *(float4*)(wrow + ks2 * 16 + h * 8 + 4) = make_float4(w4, w5, w6, w7);
      bf16x8 p;
      p[0] = (__bf16)w0; p[1] = (__bf16)w1; p[2] = (__bf16)w2;
      p[3] = (__bf16)w3; p[4] = (__bf16)w4; p[5] = (__bf16)w5;
      p[6] = (__bf16)w6; p[7] = (__bf16)w7;
      pa[ks2] = p;
    }
#pragma unroll
    for (int ks2 = 0; ks2 < 2; ++ks2) {
#pragma unroll
      for (int dsub = 0; dsub < 8; ++dsub) {
        const int d = dsub * 32 + q5;
        const int slot = (2 * ks2 + h) ^ ((d >> 1) & 3);
        bf16x8 b = *(const bf16x8*)(cur + d * 64 + slot * 16);
        oacc[dsub] =
            __builtin_amdgcn_mfma_f32_32x32x16_bf16(pa[ks2], b, oacc[dsub], 0,
                                                    0, 0);
      }
    }
    __syncthreads();
  }
#pragma unroll
  for (int dsub = 0; dsub < 8; ++dsub) {
#pragma unroll
    for (int r = 0; r < 16; ++r) {
      const int qrow = (r & 3) + 8 * (r >> 2) + 4 * h;
      outO[(size_t)(qw + qrow) * DD + dsub * 32 + q5] = oacc[dsub][r];
    }
  }
}

extern "C" void kernel_launch(void* const* d_in, const int* in_sizes, int n_in,
                              void* d_out, int out_size, void* d_ws,
                              size_t ws_size, hipStream_t stream) {
  const float* x = (const float*)d_in[0];
  const float* memory = (const float*)d_in[1];
  float* outO = (float*)d_out;           // [65536][256]
  float* outW = outO + (size_t)NQ * DD;  // [65536][2048]

  // ws layout: memb (1MB) | memTswz (1MB) | sums (256KB) | p_e (256MB bf16)
  u16* memb = (u16*)d_ws;
  u16* memTswz = memb + (size_t)MM * DD;
  float* sums = (float*)(memTswz + (size_t)MM * DD);
  u16* p_e = (u16*)(sums + NQ);
  const size_t need = (size_t)MM * DD * 2 * 2 + (size_t)NQ * 4 +
                      (size_t)NQ * MM * 2;  // ~258.25 MB

  mem_convert_kernel<<<dim3((MM * DD) / 256), dim3(256), 0, stream>>>(
      memory, memb, memTswz);
  if (ws_size >= need) {
    pass1_kernel<<<dim3(NQ / 128), dim3(256), 0, stream>>>(x, memb, memTswz,
                                                           p_e, sums, outO);
    wnorm_kernel<<<dim3((NQ * (MM / 32)) / 256), dim3(256), 0, stream>>>(
        p_e, sums, outW);
  } else {
    pass1_fb<<<dim3(NQ / 128), dim3(256), 0, stream>>>(x, memb, outW, sums);
    pass2_fb<<<dim3(NQ / 128), dim3(256), 0, stream>>>(memTswz, sums, outO,
                                                       outW);
  }
}

// Round 11
// 420.601 us; speedup vs baseline: 1.1988x; 1.1988x over previous
//
#include <hip/hip_runtime.h>
#include <hip/hip_bf16.h>
#include <stdint.h>

// x[65536][256] f32, memory[2048][256] f32
// out = [ memory_output[65536][256] | attention_weights[65536][2048] ] f32
#define NQ 65536
#define MM 2048
#define DD 256

typedef __bf16 bf16x8 __attribute__((ext_vector_type(8)));
typedef float f32x16 __attribute__((ext_vector_type(16)));
typedef unsigned short u16;
typedef unsigned int u32;
typedef u16 u16x8 __attribute__((ext_vector_type(8)));

typedef __attribute__((address_space(3))) u32 lds_u32;
typedef __attribute__((address_space(1))) u32 glb_u32;

#define GLOAD16(gsrc, ldst)                                                    \
  __builtin_amdgcn_global_load_lds((glb_u32*)(uintptr_t)(gsrc),                \
                                   (lds_u32*)(u32)(uintptr_t)(ldst), 16, 0, 0)

__device__ __forceinline__ u16 f32_to_bf16_rtne(float v) {
  u32 u = __builtin_bit_cast(u32, v);
  u += 0x7FFFu + ((u >> 16) & 1u);
  return (u16)(u >> 16);
}

// memb: row-major [2048][256] bf16.
// memTswz: per 32-m tile t (64 tiles, 16KB each):
//   u16 idx = t*8192 + (d*4 + slot)*8 + e, slot = c ^ ((d>>1)&3),
//   within-tile m = c*8 + e. (R5/R8-validated staging + PV read path.)
__global__ __launch_bounds__(256) void mem_convert_kernel(
    const float* __restrict__ memory, u16* __restrict__ memb,
    u16* __restrict__ memTswz) {
  int tid = blockIdx.x * 256 + threadIdx.x;  // 524288 total
  u16 b = f32_to_bf16_rtne(memory[tid]);
  memb[tid] = b;
  int m = tid >> 8, d = tid & 255;
  int t = m >> 5, mi = m & 31;
  int c = mi >> 3, e = mi & 7;
  int slot = c ^ ((d >> 1) & 3);
  memTswz[(size_t)t * 8192 + (size_t)(d * 4 + slot) * 8 + e] = b;
}

// p_e layout (tiled): [qt][tm][32 qrow][32 m] u16, qt = q/32, tm = m/32.
// Tile = 2KB contiguous -> pass2 stages it with one coalesced 2KB read.

// ---- Pass 1: QK + exp -> bf16 e (tiled) + sums ----
// 512 blocks x 8 waves (512 thr): 4 q-groups x 2 m-halves share one staged
// 64-row memb tile (dbuf 2x32KB). Read/compute paths identical to R5; only
// the wave->work mapping and the e-store indexing (tiled) changed.
__global__ __launch_bounds__(512, 4) void pass1_kernel(
    const float* __restrict__ x, const u16* __restrict__ memb,
    u16* __restrict__ p_e, float* __restrict__ sums) {
  __shared__ __align__(16) char stage[2][32768];
  __shared__ float lsum[4][2][32];

  const int tid = threadIdx.x;
  const int wv = tid >> 6;   // 0..7
  const int qg = wv >> 1;    // q-group 0..3
  const int mh = wv & 1;     // m-half
  const int l = tid & 63;
  const int q5 = l & 31;
  const int h = l >> 5;
  const int qw = blockIdx.x * 128 + qg * 32;
  const int qt = blockIdx.x * 4 + qg;

  bf16x8 aq[16];
  {
    const float* xrow = x + (size_t)(qw + q5) * DD;
#pragma unroll
    for (int ks = 0; ks < 16; ++ks) {
      const float4 f0 = *(const float4*)(xrow + ks * 16 + h * 8);
      const float4 f1 = *(const float4*)(xrow + ks * 16 + h * 8 + 4);
      bf16x8 a;
      a[0] = (__bf16)f0.x; a[1] = (__bf16)f0.y;
      a[2] = (__bf16)f0.z; a[3] = (__bf16)f0.w;
      a[4] = (__bf16)f1.x; a[5] = (__bf16)f1.y;
      a[6] = (__bf16)f1.z; a[7] = (__bf16)f1.w;
      aq[ks] = a;
    }
  }

  auto STAGE1 = [&](int t, char* buf) {  // 64 mem rows -> 32KB, 4 insts/wave
#pragma unroll
    for (int i = 0; i < 4; ++i) {
      const int wc = wv * 4 + i;   // 1KB chunks 0..31
      const int row = wc * 2 + h;  // 0..63
      const int csrc = q5 ^ (row & 7);
      GLOAD16(memb + (((size_t)(t * 64 + row)) << 8) + csrc * 8,
              buf + (wc << 10));
    }
  };

  float part[16];
#pragma unroll
  for (int r = 0; r < 16; ++r) part[r] = 0.f;

  STAGE1(0, stage[0]);
  __syncthreads();
  for (int t = 0; t < 32; ++t) {
    char* cur = stage[t & 1];
    char* nxt = stage[(t & 1) ^ 1];
    if (t + 1 < 32) STAGE1(t + 1, nxt);

    const int mrow = mh * 32 + q5;
    const char* bbase = cur + mrow * 512;
    const int sw = mrow & 7;
    f32x16 acc = 0.f;
    __builtin_amdgcn_s_setprio(1);
#pragma unroll
    for (int ks = 0; ks < 16; ++ks) {
      bf16x8 b = *(const bf16x8*)(bbase + (((ks * 2 + h) ^ sw) << 4));
      acc = __builtin_amdgcn_mfma_f32_32x32x16_bf16(aq[ks], b, acc, 0, 0, 0);
    }
    __builtin_amdgcn_s_setprio(0);
    const int tm = t * 2 + mh;
    u16* ptile = p_e + ((size_t)qt * 64 + tm) * 1024;  // [32q][32m] tile
#pragma unroll
    for (int r = 0; r < 16; ++r) {
      const int qrow = (r & 3) + 8 * (r >> 2) + 4 * h;
      const float e = __expf(acc[r]);
      part[r] += e;
      ptile[qrow * 32 + q5] = f32_to_bf16_rtne(e);
    }
    __syncthreads();
  }

  // butterfly over the 32 m-lanes; combine the two m-half waves via LDS
#pragma unroll
  for (int r = 0; r < 16; ++r) {
    float s = part[r];
    s += __shfl_xor(s, 1, 64);
    s += __shfl_xor(s, 2, 64);
    s += __shfl_xor(s, 4, 64);
    s += __shfl_xor(s, 8, 64);
    s += __shfl_xor(s, 16, 64);
    part[r] = s;
  }
  if (q5 == 0) {
#pragma unroll
    for (int r = 0; r < 16; ++r) {
      lsum[qg][mh][(r & 3) + 8 * (r >> 2) + 4 * h] = part[r];
    }
  }
  __syncthreads();
  if (mh == 0 && q5 == 0) {
#pragma unroll
    for (int r = 0; r < 16; ++r) {
      const int qrow = (r & 3) + 8 * (r >> 2) + 4 * h;
      sums[qw + qrow] = lsum[qg][0][qrow] + lsum[qg][1][qrow];
    }
  }
}

// ---- Pass 2: W = e*inv + O = (e*M)*inv ----
// 512 blocks x 8 waves (512 thr): 4 q-groups x 2 d-halves. memT staged
// dbuf 2x16KB shared by all; P-tile (2KB/group) staged by dh0 wave into
// pad-40 LDS, read as pa frags by both d-waves; W stored by dh1 wave.
// oacc[4] keeps VGPR under the 128 cap (4 waves/SIMD).
__global__ __launch_bounds__(512, 4) void pass2_kernel(
    const u16* __restrict__ p_e, const u16* __restrict__ memTswz,
    const float* __restrict__ sums, float* __restrict__ outO,
    float* __restrict__ outW) {
  __shared__ __align__(16) char mt[2][16384];
  __shared__ __align__(16) u16 plds[2][4][32][40];  // dbuf x qg x 32 x pitch40

  const int tid = threadIdx.x;
  const int wv = tid >> 6;   // 0..7
  const int qg = wv >> 1;    // q-group 0..3
  const int dh = wv & 1;     // d-half
  const int l = tid & 63;
  const int q5 = l & 31;
  const int h = l >> 5;
  const int qw = blockIdx.x * 128 + qg * 32;
  const int qt = blockIdx.x * 4 + qg;

  const float inv_lane = 1.0f / sums[qw + q5];
  float invr[16];
#pragma unroll
  for (int r = 0; r < 16; ++r) {
    invr[r] = __shfl(inv_lane, (r & 3) + 8 * (r >> 2) + 4 * h, 64);
  }

  auto STAGE_MT = [&](int t, char* buf) {  // 16KB memT tile, 2 insts/wave
#pragma unroll
    for (int i = 0; i < 2; ++i) {
      const int ci = wv * 2 + i;  // 1KB chunks 0..15
      GLOAD16(memTswz + ((size_t)t * 1024 + ci * 64 + l) * 8, buf + (ci << 10));
    }
  };

  // P-tile staging (dh0 wave): lane covers (row = l>>1, 32B half = l&1)
  const int prow = l >> 1;
  const int phalf = l & 1;
  u16x8 pr0, pr1;
  auto PLOAD = [&](int t) {
    const u16* psrc =
        p_e + ((size_t)qt * 64 + t) * 1024 + prow * 32 + phalf * 16;
    pr0 = *(const u16x8*)psrc;
    pr1 = *(const u16x8*)(psrc + 8);
  };
  auto PWRITE = [&](int b) {
    *(u16x8*)&plds[b][qg][prow][phalf * 16] = pr0;
    *(u16x8*)&plds[b][qg][prow][phalf * 16 + 8] = pr1;
  };

  f32x16 oacc[4];
#pragma unroll
  for (int i = 0; i < 4; ++i) oacc[i] = 0.f;

  STAGE_MT(0, mt[0]);
  if (dh == 0) {
    PLOAD(0);
    PWRITE(0);
  }
  __syncthreads();
  for (int t = 0; t < 64; ++t) {
    const int cur = t & 1;
    if (t + 1 < 64) {
      STAGE_MT(t + 1, mt[cur ^ 1]);
      if (dh == 0) PLOAD(t + 1);  // issue early; ds_write after compute (T14)
    }

    bf16x8 pa[2];
#pragma unroll
    for (int ks2 = 0; ks2 < 2; ++ks2) {
      pa[ks2] = *(const bf16x8*)&plds[cur][qg][q5][ks2 * 16 + h * 8];
    }

    if (dh == 1) {  // W = f32(e_bf16) * inv, coalesced float4 stores
#pragma unroll
      for (int ks2 = 0; ks2 < 2; ++ks2) {
        const u16x8 pe = __builtin_bit_cast(u16x8, pa[ks2]);
        float w[8];
#pragma unroll
        for (int j = 0; j < 8; ++j) {
          w[j] = __builtin_bit_cast(float, (u32)pe[j] << 16) * inv_lane;
        }
        float* base =
            outW + (size_t)(qw + q5) * MM + t * 32 + ks2 * 16 + h * 8;
        *(float4*)base = make_float4(w[0], w[1], w[2], w[3]);
        *(float4*)(base + 4) = make_float4(w[4], w[5], w[6], w[7]);
      }
    }

    const char* ct = mt[cur];
    __builtin_amdgcn_s_setprio(1);
#pragma unroll
    for (int ks2 = 0; ks2 < 2; ++ks2) {
#pragma unroll
      for (int i = 0; i < 4; ++i) {
        const int d = (dh * 4 + i) * 32 + q5;
        const int slot = (2 * ks2 + h) ^ ((d >> 1) & 3);
        bf16x8 b = *(const bf16x8*)(ct + d * 64 + slot * 16);
        oacc[i] =
            __builtin_amdgcn_mfma_f32_32x32x16_bf16(pa[ks2], b, oacc[i], 0, 0,
                                                    0);
      }
    }
    __builtin_amdgcn_s_setprio(0);
    if (t + 1 < 64 && dh == 0) PWRITE(cur ^ 1);
    __syncthreads();
  }

#pragma unroll
  for (int i = 0; i < 4; ++i) {
#pragma unroll
    for (int r = 0; r < 16; ++r) {
      const int qrow = (r & 3) + 8 * (r >> 2) + 4 * h;
      outO[(size_t)(qw + qrow) * DD + (dh * 4 + i) * 32 + q5] =
          oacc[i][r] * invr[r];
    }
  }
}

// ---- Fallback (ws too small): f32-roundtrip via outW (R4/R5-validated) ----
__global__ __launch_bounds__(256, 2) void pass1_fb(
    const float* __restrict__ x, const u16* __restrict__ memb,
    float* __restrict__ outWf, float* __restrict__ sums) {
  __shared__ __align__(16) char stage[2][32768];
  const int tid = threadIdx.x;
  const int wv = tid >> 6;
  const int l = tid & 63;
  const int q5 = l & 31;
  const int h = l >> 5;
  const int qw = blockIdx.x * 128 + wv * 32;

  bf16x8 aq[16];
  {
    const float* xrow = x + (size_t)(qw + q5) * DD;
#pragma unroll
    for (int ks = 0; ks < 16; ++ks) {
      const float4 f0 = *(const float4*)(xrow + ks * 16 + h * 8);
      const float4 f1 = *(const float4*)(xrow + ks * 16 + h * 8 + 4);
      bf16x8 a;
      a[0] = (__bf16)f0.x; a[1] = (__bf16)f0.y;
      a[2] = (__bf16)f0.z; a[3] = (__bf16)f0.w;
      a[4] = (__bf16)f1.x; a[5] = (__bf16)f1.y;
      a[6] = (__bf16)f1.z; a[7] = (__bf16)f1.w;
      aq[ks] = a;
    }
  }
  auto STAGE1 = [&](int mt, char* buf) {
#pragma unroll
    for (int i = 0; i < 8; ++i) {
      const int wc = wv * 8 + i;
      const int row = wc * 2 + h;
      const int csrc = q5 ^ (row & 7);
      GLOAD16(memb + (((size_t)(mt * 64 + row)) << 8) + csrc * 8,
              buf + (wc << 10));
    }
  };
  float part[16];
#pragma unroll
  for (int r = 0; r < 16; ++r) part[r] = 0.f;
  STAGE1(0, stage[0]);
  __syncthreads();
  for (int mt = 0; mt < 32; ++mt) {
    char* cur = stage[mt & 1];
    char* nxt = stage[(mt & 1) ^ 1];
    if (mt + 1 < 32) STAGE1(mt + 1, nxt);
#pragma unroll
    for (int msub = 0; msub < 2; ++msub) {
      const int mrow = msub * 32 + q5;
      const char* bbase = cur + mrow * 512;
      const int sw = mrow & 7;
      f32x16 acc = 0.f;
#pragma unroll
      for (int ks = 0; ks < 16; ++ks) {
        bf16x8 b = *(const bf16x8*)(bbase + (((ks * 2 + h) ^ sw) << 4));
        acc = __builtin_amdgcn_mfma_f32_32x32x16_bf16(aq[ks], b, acc, 0, 0, 0);
      }
      const int tm = mt * 2 + msub;
#pragma unroll
      for (int r = 0; r < 16; ++r) {
        const int qrow = (r & 3) + 8 * (r >> 2) + 4 * h;
        const float e = __expf(acc[r]);
        part[r] += e;
        outWf[(size_t)(qw + qrow) * MM + tm * 32 + q5] = e;
      }
    }
    __syncthreads();
  }
#pragma unroll
  for (int r = 0; r < 16; ++r) {
    float s = part[r];
    s += __shfl_xor(s, 1, 64);
    s += __shfl_xor(s, 2, 64);
    s += __shfl_xor(s, 4, 64);
    s += __shfl_xor(s, 8, 64);
    s += __shfl_xor(s, 16, 64);
    if (q5 == 0) sums[qw + (r & 3) + 8 * (r >> 2) + 4 * h] = s;
  }
}

__global__ __launch_bounds__(256, 2) void pass2_fb(
    const u16* __restrict__ memTswz, const float* __restrict__ sums,
    float* __restrict__ outO, float* __restrict__ outW) {
  __shared__ __align__(16) char tstage[2][16384];
  const int tid = threadIdx.x;
  const int wv = tid >> 6;
  const int l = tid & 63;
  const int q5 = l & 31;
  const int h = l >> 5;
  const int qw = blockIdx.x * 128 + wv * 32;
  const float inv_lane = 1.0f / sums[qw + q5];
  auto STAGE = [&](int t, char* buf) {
#pragma unroll
    for (int i = 0; i < 4; ++i) {
      const int ci = wv * 4 + i;
      GLOAD16(memTswz + ((size_t)t * 1024 + ci * 64 + l) * 8, buf + (ci << 10));
    }
  };
  f32x16 oacc[8];
#pragma unroll
  for (int i = 0; i < 8; ++i) oacc[i] = 0.f;
  STAGE(0, tstage[0]);
  __syncthreads();
  for (int tm = 0; tm < 64; ++tm) {
    char* cur = tstage[tm & 1];
    char* nxt = tstage[(tm & 1) ^ 1];
    if (tm + 1 < 64) STAGE(tm + 1, nxt);
    float* wrow = outW + (size_t)(qw + q5) * MM + tm * 32;
    bf16x8 pa[2];
#pragma unroll
    for (int ks2 = 0; ks2 < 2; ++ks2) {
      float4 f0 = *(const float4*)(wrow + ks2 * 16 + h * 8);
      float4 f1 = *(const float4*)(wrow + ks2 * 16 + h * 8 + 4);
      float w0 = f0.x * inv_lane, w1 = f0.y * inv_lane;
      float w2 = f0.z * inv_lane, w3 = f0.w * inv_lane;
      float w4 = f1.x * inv_lane, w5 = f1.y * inv_lane;
      float w6 = f1.z * inv_lane, w7 = f1.w * inv_lane;
      *(float4*)(wrow + ks2 * 16 + h * 8) = make_float4(w0, w1, w2, w3);
      *(float4*)(wrow + ks2 * 16 + h * 8 + 4) = make_float4(w4, w5, w6, w7);
      bf16x8 p;
      p[0] = (__bf16)w0; p[1] = (__bf16)w1; p[2] = (__bf16)w2;
      p[3] = (__bf16)w3; p[4] = (__bf16)w4; p[5] = (__bf16)w5;
      p[6] = (__bf16)w6; p[7] = (__bf16)w7;
      pa[ks2] = p;
    }
#pragma unroll
    for (int ks2 = 0; ks2 < 2; ++ks2) {
#pragma unroll
      for (int dsub = 0; dsub < 8; ++dsub) {
        const int d = dsub * 32 + q5;
        const int slot = (2 * ks2 + h) ^ ((d >> 1) & 3);
        bf16x8 b = *(const bf16x8*)(cur + d * 64 + slot * 16);
        oacc[dsub] =
            __builtin_amdgcn_mfma_f32_32x32x16_bf16(pa[ks2], b, oacc[dsub], 0,
                                                    0, 0);
      }
    }
    __syncthreads();
  }
#pragma unroll
  for (int dsub = 0; dsub < 8; ++dsub) {
#pragma unroll
    for (int r = 0; r < 16; ++r) {
      const int qrow = (r & 3) + 8 * (r >> 2) + 4 * h;
      outO[(size_t)(qw + qrow) * DD + dsub * 32 + q5] = oacc[dsub][r];
    }
  }
}

extern "C" void kernel_launch(void* const* d_in, const int* in_sizes, int n_in,
                              void* d_out, int out_size, void* d_ws,
                              size_t ws_size, hipStream_t stream) {
  const float* x = (const float*)d_in[0];
  const float* memory = (const float*)d_in[1];
  float* outO = (float*)d_out;           // [65536][256]
  float* outW = outO + (size_t)NQ * DD;  // [65536][2048]

  // ws layout: memb (1MB) | memTswz (1MB) | sums (256KB) | p_e (256MB bf16)
  u16* memb = (u16*)d_ws;
  u16* memTswz = memb + (size_t)MM * DD;
  float* sums = (float*)(memTswz + (size_t)MM * DD);
  u16* p_e = (u16*)(sums + NQ);
  const size_t need = (size_t)MM * DD * 2 * 2 + (size_t)NQ * 4 +
                      (size_t)NQ * MM * 2;  // ~258.25 MB

  mem_convert_kernel<<<dim3((MM * DD) / 256), dim3(256), 0, stream>>>(
      memory, memb, memTswz);
  if (ws_size >= need) {
    pass1_kernel<<<dim3(NQ / 128), dim3(512), 0, stream>>>(x, memb, p_e, sums);
    pass2_kernel<<<dim3(NQ / 128), dim3(512), 0, stream>>>(p_e, memTswz, sums,
                                                           outO, outW);
  } else {
    pass1_fb<<<dim3(NQ / 128), dim3(256), 0, stream>>>(x, memb, outW, sums);
    pass2_fb<<<dim3(NQ / 128), dim3(256), 0, stream>>>(memTswz, sums, outO,
                                                       outW);
  }
}

// Round 12
// 359.516 us; speedup vs baseline: 1.4025x; 1.1699x over previous
//
#include <hip/hip_runtime.h>
#include <hip/hip_bf16.h>
#include <stdint.h>

// x[65536][256] f32, memory[2048][256] f32
// out = [ memory_output[65536][256] | attention_weights[65536][2048] ] f32
#define NQ 65536
#define MM 2048
#define DD 256

typedef __bf16 bf16x8 __attribute__((ext_vector_type(8)));
typedef float f32x16 __attribute__((ext_vector_type(16)));
typedef unsigned short u16;
typedef unsigned int u32;
typedef u16 u16x8 __attribute__((ext_vector_type(8)));

typedef __attribute__((address_space(3))) u32 lds_u32;
typedef __attribute__((address_space(1))) u32 glb_u32;

#define GLOAD16(gsrc, ldst)                                                    \
  __builtin_amdgcn_global_load_lds((glb_u32*)(uintptr_t)(gsrc),                \
                                   (lds_u32*)(u32)(uintptr_t)(ldst), 16, 0, 0)

__device__ __forceinline__ u16 f32_to_bf16_rtne(float v) {
  u32 u = __builtin_bit_cast(u32, v);
  u += 0x7FFFu + ((u >> 16) & 1u);
  return (u16)(u >> 16);
}

// memb: row-major [2048][256] bf16.
// memTswz: per 32-m tile t (64 tiles, 16KB each):
//   u16 idx = t*8192 + (d*4 + slot)*8 + e, slot = c ^ ((d>>1)&3),
//   within-tile m = c*8 + e. (R5/R8-validated staging + PV read path.)
__global__ __launch_bounds__(256) void mem_convert_kernel(
    const float* __restrict__ memory, u16* __restrict__ memb,
    u16* __restrict__ memTswz) {
  int tid = blockIdx.x * 256 + threadIdx.x;  // 524288 total
  u16 b = f32_to_bf16_rtne(memory[tid]);
  memb[tid] = b;
  int m = tid >> 8, d = tid & 255;
  int t = m >> 5, mi = m & 31;
  int c = mi >> 3, e = mi & 7;
  int slot = c ^ ((d >> 1) & 3);
  memTswz[(size_t)t * 8192 + (size_t)(d * 4 + slot) * 8 + e] = b;
}

// p_e layout (tiled): [qt][tm][32 qrow][32 m] u16 (2KB contiguous tiles).
// In-tile byte offset for lane (q5,h), frag ks2: q5*64 + ks2*32 + h*16 —
// coalesced on both the pass1 store and pass2 load sides.

// ---- Pass 1: QK + exp -> bf16 e (tiled, coalesced via plds) + sums ----
// 512 blocks x 4 waves x 32q; dbuf 2x32KB (R8/R5-validated). e goes through
// the R2-validated padded plds transpose, then 2x16B coalesced stores.
__global__ __launch_bounds__(256, 2) void pass1_kernel(
    const float* __restrict__ x, const u16* __restrict__ memb,
    u16* __restrict__ p_e, float* __restrict__ sums) {
  __shared__ __align__(16) char stage[2][32768];
  __shared__ __align__(16) u16 plds[4][32][40];  // 80B pitch (R2-validated)

  const int tid = threadIdx.x;
  const int wv = tid >> 6;
  const int l = tid & 63;
  const int q5 = l & 31;
  const int h = l >> 5;
  const int qw = blockIdx.x * 128 + wv * 32;
  const int qt = blockIdx.x * 4 + wv;

  bf16x8 aq[16];
  {
    const float* xrow = x + (size_t)(qw + q5) * DD;
#pragma unroll
    for (int ks = 0; ks < 16; ++ks) {
      const float4 f0 = *(const float4*)(xrow + ks * 16 + h * 8);
      const float4 f1 = *(const float4*)(xrow + ks * 16 + h * 8 + 4);
      bf16x8 a;
      a[0] = (__bf16)f0.x; a[1] = (__bf16)f0.y;
      a[2] = (__bf16)f0.z; a[3] = (__bf16)f0.w;
      a[4] = (__bf16)f1.x; a[5] = (__bf16)f1.y;
      a[6] = (__bf16)f1.z; a[7] = (__bf16)f1.w;
      aq[ks] = a;
    }
  }

  auto STAGE1 = [&](int mt, char* buf) {  // 64 mem rows -> 32KB
#pragma unroll
    for (int i = 0; i < 8; ++i) {
      const int wc = wv * 8 + i;
      const int row = wc * 2 + h;
      const int csrc = q5 ^ (row & 7);
      GLOAD16(memb + (((size_t)(mt * 64 + row)) << 8) + csrc * 8,
              buf + (wc << 10));
    }
  };

  float part[16];
#pragma unroll
  for (int r = 0; r < 16; ++r) part[r] = 0.f;

  STAGE1(0, stage[0]);
  __syncthreads();
  for (int mt = 0; mt < 32; ++mt) {
    char* cur = stage[mt & 1];
    char* nxt = stage[(mt & 1) ^ 1];
    if (mt + 1 < 32) STAGE1(mt + 1, nxt);
#pragma unroll
    for (int msub = 0; msub < 2; ++msub) {
      const int mrow = msub * 32 + q5;
      const char* bbase = cur + mrow * 512;
      const int sw = mrow & 7;
      f32x16 acc = 0.f;
      __builtin_amdgcn_s_setprio(1);
#pragma unroll
      for (int ks = 0; ks < 16; ++ks) {
        bf16x8 b = *(const bf16x8*)(bbase + (((ks * 2 + h) ^ sw) << 4));
        acc = __builtin_amdgcn_mfma_f32_32x32x16_bf16(aq[ks], b, acc, 0, 0, 0);
      }
      __builtin_amdgcn_s_setprio(0);
      // exp -> rowsum parts + plds (C/D layout scatter, wave-private)
#pragma unroll
      for (int r = 0; r < 16; ++r) {
        const int qrow = (r & 3) + 8 * (r >> 2) + 4 * h;
        const float e = __expf(acc[r]);
        part[r] += e;
        plds[wv][qrow][q5] = f32_to_bf16_rtne(e);
      }
      // wave-private roundtrip: drain DS writes before reads
      asm volatile("s_waitcnt lgkmcnt(0)" ::: "memory");
      __builtin_amdgcn_sched_barrier(0);
      // coalesced tiled store: lane (q5,h) holds P[q5][frag] after transpose
      const int tm = mt * 2 + msub;
      u16* ptile = p_e + ((size_t)qt * 64 + tm) * 1024;
#pragma unroll
      for (int ks2 = 0; ks2 < 2; ++ks2) {
        const u16x8 pa = *(const u16x8*)&plds[wv][q5][ks2 * 16 + h * 8];
        *(u16x8*)(ptile + q5 * 32 + ks2 * 16 + h * 8) = pa;
      }
    }
    __syncthreads();
  }

#pragma unroll
  for (int r = 0; r < 16; ++r) {
    float p = part[r];
    p += __shfl_xor(p, 1, 64);
    p += __shfl_xor(p, 2, 64);
    p += __shfl_xor(p, 4, 64);
    p += __shfl_xor(p, 8, 64);
    p += __shfl_xor(p, 16, 64);
    if (q5 == 0) sums[qw + (r & 3) + 8 * (r >> 2) + 4 * h] = p;
  }
}

// ---- Pass 2: W = e*inv + O = (e*M)*inv (R8 structure, tiled p_e) ----
// 512 blocks x 4 waves x 32q; tm-pairs (32 steps, dbuf 2x32KB); p_e frags
// reg-prefetched one pair ahead with fully coalesced 16B loads.
__global__ __launch_bounds__(256, 2) void pass2_kernel(
    const u16* __restrict__ p_e, const u16* __restrict__ memTswz,
    const float* __restrict__ sums, float* __restrict__ outO,
    float* __restrict__ outW) {
  __shared__ __align__(16) char tstage[2][32768];

  const int tid = threadIdx.x;
  const int wv = tid >> 6;
  const int l = tid & 63;
  const int q5 = l & 31;
  const int h = l >> 5;
  const int qw = blockIdx.x * 128 + wv * 32;
  const int qt = blockIdx.x * 4 + wv;

  const float inv_lane = 1.0f / sums[qw + q5];
  float invr[16];
#pragma unroll
  for (int r = 0; r < 16; ++r) {
    invr[r] = __shfl(inv_lane, (r & 3) + 8 * (r >> 2) + 4 * h, 64);
  }

  auto STAGE2T = [&](int pr, char* buf) {  // tiles 2pr,2pr+1 -> 32KB linear
#pragma unroll
    for (int i = 0; i < 8; ++i) {
      const int ci = wv * 8 + i;
      GLOAD16(memTswz + ((size_t)pr * 2048 + ci * 64 + l) * 8,
              buf + (ci << 10));
    }
  };

  // tiled p_e: lane's frag at tile + q5*32 + ks2*16 + h*8 (u16 units)
  const u16* pbase = p_e + (size_t)qt * 64 * 1024 + q5 * 32 + h * 8;
  u16x8 pec[4], pen[4];  // [tmi*2 + ks2], current / next pair
#pragma unroll
  for (int j = 0; j < 4; ++j) {
    pec[j] = *(const u16x8*)(pbase + (size_t)(j >> 1) * 1024 + (j & 1) * 16);
  }

  f32x16 oacc[8];
#pragma unroll
  for (int i = 0; i < 8; ++i) oacc[i] = 0.f;

  STAGE2T(0, tstage[0]);
  __syncthreads();
  for (int pr = 0; pr < 32; ++pr) {
    char* cur = tstage[pr & 1];
    char* nxt = tstage[(pr & 1) ^ 1];
    if (pr + 1 < 32) {
      STAGE2T(pr + 1, nxt);
      const u16* pnext = pbase + (size_t)(pr + 1) * 2048;
#pragma unroll
      for (int j = 0; j < 4; ++j) {
        pen[j] =
            *(const u16x8*)(pnext + (size_t)(j >> 1) * 1024 + (j & 1) * 16);
      }
    }

#pragma unroll
    for (int tmi = 0; tmi < 2; ++tmi) {
      const char* ct = cur + tmi * 16384;
      // W = f32(e)*inv, coalesced float4 stores (row q5 of this wave)
#pragma unroll
      for (int ks2 = 0; ks2 < 2; ++ks2) {
        const u16x8 pe = pec[tmi * 2 + ks2];
        float w[8];
#pragma unroll
        for (int j = 0; j < 8; ++j) {
          w[j] = __builtin_bit_cast(float, (u32)pe[j] << 16) * inv_lane;
        }
        float* base = outW + (size_t)(qw + q5) * MM + (pr * 2 + tmi) * 32 +
                      ks2 * 16 + h * 8;
        *(float4*)base = make_float4(w[0], w[1], w[2], w[3]);
        *(float4*)(base + 4) = make_float4(w[4], w[5], w[6], w[7]);
      }
      __builtin_amdgcn_s_setprio(1);
#pragma unroll
      for (int ks2 = 0; ks2 < 2; ++ks2) {
        const bf16x8 pa = __builtin_bit_cast(bf16x8, pec[tmi * 2 + ks2]);
#pragma unroll
        for (int dsub = 0; dsub < 8; ++dsub) {
          const int d = dsub * 32 + q5;
          const int slot = (2 * ks2 + h) ^ ((d >> 1) & 3);
          bf16x8 b = *(const bf16x8*)(ct + d * 64 + slot * 16);
          oacc[dsub] = __builtin_amdgcn_mfma_f32_32x32x16_bf16(pa, b,
                                                               oacc[dsub], 0,
                                                               0, 0);
        }
      }
      __builtin_amdgcn_s_setprio(0);
    }
    __syncthreads();
#pragma unroll
    for (int j = 0; j < 4; ++j) pec[j] = pen[j];
  }

#pragma unroll
  for (int dsub = 0; dsub < 8; ++dsub) {
#pragma unroll
    for (int r = 0; r < 16; ++r) {
      const int qrow = (r & 3) + 8 * (r >> 2) + 4 * h;
      outO[(size_t)(qw + qrow) * DD + dsub * 32 + q5] = oacc[dsub][r] * invr[r];
    }
  }
}

// ---- Fallback (ws too small): f32-roundtrip via outW (R4/R5-validated) ----
__global__ __launch_bounds__(256, 2) void pass1_fb(
    const float* __restrict__ x, const u16* __restrict__ memb,
    float* __restrict__ outWf, float* __restrict__ sums) {
  __shared__ __align__(16) char stage[2][32768];
  const int tid = threadIdx.x;
  const int wv = tid >> 6;
  const int l = tid & 63;
  const int q5 = l & 31;
  const int h = l >> 5;
  const int qw = blockIdx.x * 128 + wv * 32;

  bf16x8 aq[16];
  {
    const float* xrow = x + (size_t)(qw + q5) * DD;
#pragma unroll
    for (int ks = 0; ks < 16; ++ks) {
      const float4 f0 = *(const float4*)(xrow + ks * 16 + h * 8);
      const float4 f1 = *(const float4*)(xrow + ks * 16 + h * 8 + 4);
      bf16x8 a;
      a[0] = (__bf16)f0.x; a[1] = (__bf16)f0.y;
      a[2] = (__bf16)f0.z; a[3] = (__bf16)f0.w;
      a[4] = (__bf16)f1.x; a[5] = (__bf16)f1.y;
      a[6] = (__bf16)f1.z; a[7] = (__bf16)f1.w;
      aq[ks] = a;
    }
  }
  auto STAGE1 = [&](int mt, char* buf) {
#pragma unroll
    for (int i = 0; i < 8; ++i) {
      const int wc = wv * 8 + i;
      const int row = wc * 2 + h;
      const int csrc = q5 ^ (row & 7);
      GLOAD16(memb + (((size_t)(mt * 64 + row)) << 8) + csrc * 8,
              buf + (wc << 10));
    }
  };
  float part[16];
#pragma unroll
  for (int r = 0; r < 16; ++r) part[r] = 0.f;
  STAGE1(0, stage[0]);
  __syncthreads();
  for (int mt = 0; mt < 32; ++mt) {
    char* cur = stage[mt & 1];
    char* nxt = stage[(mt & 1) ^ 1];
    if (mt + 1 < 32) STAGE1(mt + 1, nxt);
#pragma unroll
    for (int msub = 0; msub < 2; ++msub) {
      const int mrow = msub * 32 + q5;
      const char* bbase = cur + mrow * 512;
      const int sw = mrow & 7;
      f32x16 acc = 0.f;
#pragma unroll
      for (int ks = 0; ks < 16; ++ks) {
        bf16x8 b = *(const bf16x8*)(bbase + (((ks * 2 + h) ^ sw) << 4));
        acc = __builtin_amdgcn_mfma_f32_32x32x16_bf16(aq[ks], b, acc, 0, 0, 0);
      }
      const int tm = mt * 2 + msub;
#pragma unroll
      for (int r = 0; r < 16; ++r) {
        const int qrow = (r & 3) + 8 * (r >> 2) + 4 * h;
        const float e = __expf(acc[r]);
        part[r] += e;
        outWf[(size_t)(qw + qrow) * MM + tm * 32 + q5] = e;
      }
    }
    __syncthreads();
  }
#pragma unroll
  for (int r = 0; r < 16; ++r) {
    float s = part[r];
    s += __shfl_xor(s, 1, 64);
    s += __shfl_xor(s, 2, 64);
    s += __shfl_xor(s, 4, 64);
    s += __shfl_xor(s, 8, 64);
    s += __shfl_xor(s, 16, 64);
    if (q5 == 0) sums[qw + (r & 3) + 8 * (r >> 2) + 4 * h] = s;
  }
}

__global__ __launch_bounds__(256, 2) void pass2_fb(
    const u16* __restrict__ memTswz, const float* __restrict__ sums,
    float* __restrict__ outO, float* __restrict__ outW) {
  __shared__ __align__(16) char tstage[2][16384];
  const int tid = threadIdx.x;
  const int wv = tid >> 6;
  const int l = tid & 63;
  const int q5 = l & 31;
  const int h = l >> 5;
  const int qw = blockIdx.x * 128 + wv * 32;
  const float inv_lane = 1.0f / sums[qw + q5];
  auto STAGE = [&](int t, char* buf) {
#pragma unroll
    for (int i = 0; i < 4; ++i) {
      const int ci = wv * 4 + i;
      GLOAD16(memTswz + ((size_t)t * 1024 + ci * 64 + l) * 8, buf + (ci << 10));
    }
  };
  f32x16 oacc[8];
#pragma unroll
  for (int i = 0; i < 8; ++i) oacc[i] = 0.f;
  STAGE(0, tstage[0]);
  __syncthreads();
  for (int tm = 0; tm < 64; ++tm) {
    char* cur = tstage[tm & 1];
    char* nxt = tstage[(tm & 1) ^ 1];
    if (tm + 1 < 64) STAGE(tm + 1, nxt);
    float* wrow = outW + (size_t)(qw + q5) * MM + tm * 32;
    bf16x8 pa[2];
#pragma unroll
    for (int ks2 = 0; ks2 < 2; ++ks2) {
      float4 f0 = *(const float4*)(wrow + ks2 * 16 + h * 8);
      float4 f1 = *(const float4*)(wrow + ks2 * 16 + h * 8 + 4);
      float w0 = f0.x * inv_lane, w1 = f0.y * inv_lane;
      float w2 = f0.z * inv_lane, w3 = f0.w * inv_lane;
      float w4 = f1.x * inv_lane, w5 = f1.y * inv_lane;
      float w6 = f1.z * inv_lane, w7 = f1.w * inv_lane;
      *(float4*)(wrow + ks2 * 16 + h * 8) = make_float4(w0, w1, w2, w3);
      *(float4*)(wrow + ks2 * 16 + h * 8 + 4) = make_float4(w4, w5, w6, w7);
      bf16x8 p;
      p[0] = (__bf16)w0; p[1] = (__bf16)w1; p[2] = (__bf16)w2;
      p[3] = (__bf16)w3; p[4] = (__bf16)w4; p[5] = (__bf16)w5;
      p[6] = (__bf16)w6; p[7] = (__bf16)w7;
      pa[ks2] = p;
    }
#pragma unroll
    for (int ks2 = 0; ks2 < 2; ++ks2) {
#pragma unroll
      for (int dsub = 0; dsub < 8; ++dsub) {
        const int d = dsub * 32 + q5;
        const int slot = (2 * ks2 + h) ^ ((d >> 1) & 3);
        bf16x8 b = *(const bf16x8*)(cur + d * 64 + slot * 16);
        oacc[dsub] =
            __builtin_amdgcn_mfma_f32_32x32x16_bf16(pa[ks2], b, oacc[dsub], 0,
                                                    0, 0);
      }
    }
    __syncthreads();
  }
#pragma unroll
  for (int dsub = 0; dsub < 8; ++dsub) {
#pragma unroll
    for (int r = 0; r < 16; ++r) {
      const int qrow = (r & 3) + 8 * (r >> 2) + 4 * h;
      outO[(size_t)(qw + qrow) * DD + dsub * 32 + q5] = oacc[dsub][r];
    }
  }
}

extern "C" void kernel_launch(void* const* d_in, const int* in_sizes, int n_in,
                              void* d_out, int out_size, void* d_ws,
                              size_t ws_size, hipStream_t stream) {
  const float* x = (const float*)d_in[0];
  const float* memory = (const float*)d_in[1];
  float* outO = (float*)d_out;           // [65536][256]
  float* outW = outO + (size_t)NQ * DD;  // [65536][2048]

  // ws layout: memb (1MB) | memTswz (1MB) | sums (256KB) | p_e (256MB bf16)
  u16* memb = (u16*)d_ws;
  u16* memTswz = memb + (size_t)MM * DD;
  float* sums = (float*)(memTswz + (size_t)MM * DD);
  u16* p_e = (u16*)(sums + NQ);
  const size_t need = (size_t)MM * DD * 2 * 2 + (size_t)NQ * 4 +
                      (size_t)NQ * MM * 2;  // ~258.25 MB

  mem_convert_kernel<<<dim3((MM * DD) / 256), dim3(256), 0, stream>>>(
      memory, memb, memTswz);
  if (ws_size >= need) {
    pass1_kernel<<<dim3(NQ / 128), dim3(256), 0, stream>>>(x, memb, p_e, sums);
    pass2_kernel<<<dim3(NQ / 128), dim3(256), 0, stream>>>(p_e, memTswz, sums,
                                                           outO, outW);
  } else {
    pass1_fb<<<dim3(NQ / 128), dim3(256), 0, stream>>>(x, memb, outW, sums);
    pass2_fb<<<dim3(NQ / 128), dim3(256), 0, stream>>>(memTswz, sums, outO,
                                                       outW);
  }
}